// Round 10
// baseline (5069.861 us; speedup 1.0000x reference)
//
#include <hip/hip_runtime.h>

#define NV 100000
#define ND 300
#define NH 512
#define NB 25
#define NT 600
#define NM 15000   // NB*NT
#define NG 1536    // 3*NH

typedef _Float16 v8h __attribute__((ext_vector_type(8)));
typedef _Float16 v4h __attribute__((ext_vector_type(4)));
typedef _Float16 v2h __attribute__((ext_vector_type(2)));
typedef float    v4f __attribute__((ext_vector_type(4)));
typedef int      v4i __attribute__((ext_vector_type(4)));
typedef unsigned long long ull;

static __device__ __forceinline__ float fsigmoid(float x) {
  return __builtin_amdgcn_rcpf(1.f + __expf(-x));
}
static __device__ __forceinline__ float ftanh(float x) {
  return 1.f - 2.f * __builtin_amdgcn_rcpf(1.f + __expf(2.f * x));
}

// ---------------- GEMM: Cxg[m][n] = emb[words[m]]·w_ih0[n] + b_ih0[n], f16 out ----
__global__ __launch_bounds__(256) void k_gemm0(
    const int* __restrict__ words, const float* __restrict__ emb,
    const float* __restrict__ Bw, const float* __restrict__ bias,
    _Float16* __restrict__ Cxg, ull* __restrict__ PAYZ)
{
  // zero tagged payload buffers (2 layers x 2 parities x 6400 ull) AND the
  // 4 rendezvous counters (64 ull right after). Plain stores: kernel-end L2
  // writeback orders them before the scan's MALL-direct reads (r9-validated).
  if (blockIdx.y == 0 && blockIdx.x < 101)
    PAYZ[blockIdx.x * 256 + threadIdx.x] = 0ull;

  constexpr int K = ND;
  constexpr int NKT = (K + 31) / 32;
  __shared__ _Float16 As[128][40];
  __shared__ _Float16 Bh[128][40];
  __shared__ _Float16 Bl[128][40];
  const int tid = threadIdx.x;
  const int m0 = blockIdx.x * 128, n0 = blockIdx.y * 128;
  const int w = tid >> 6, l = tid & 63;
  const int wm = w >> 1, wn = w & 1;
  const int l15 = l & 15, q = l >> 4;

  v4f accH[4][4], accL[4][4];
  for (int a = 0; a < 4; ++a)
    for (int b = 0; b < 4; ++b) {
      v4f z = {0.f, 0.f, 0.f, 0.f};
      accH[a][b] = z; accL[a][b] = z;
    }

#pragma unroll 1
  for (int kt = 0; kt < NKT; ++kt) {
    const int kb = kt * 32;
    for (int jj = 0; jj < 4; ++jj) {
      const int F = tid + 256 * jj;
      const int row = F >> 3;
      const int kl = (F & 7) * 4;
      {
        const int m = m0 + row;
        float x0 = 0.f, x1 = 0.f, x2 = 0.f, x3 = 0.f;
        if (m < NM) {
          const int word = words[m];
          const float* ap = emb + (long)word * ND + kb + kl;
          if (kb + kl + 3 < K) {
            float4 v = *(const float4*)ap;
            x0 = v.x; x1 = v.y; x2 = v.z; x3 = v.w;
          } else {
            if (kb + kl + 0 < K) x0 = ap[0];
            if (kb + kl + 1 < K) x1 = ap[1];
            if (kb + kl + 2 < K) x2 = ap[2];
            if (kb + kl + 3 < K) x3 = ap[3];
          }
        }
        v4h hv; hv[0]=(_Float16)x0; hv[1]=(_Float16)x1; hv[2]=(_Float16)x2; hv[3]=(_Float16)x3;
        *(v4h*)&As[row][kl] = hv;
      }
      {
        const int n = n0 + row;
        const float* bp = Bw + (long)n * K + kb + kl;
        float x[4] = {0.f, 0.f, 0.f, 0.f};
        if (kb + kl + 3 < K) {
          float4 v = *(const float4*)bp;
          x[0] = v.x; x[1] = v.y; x[2] = v.z; x[3] = v.w;
        } else {
          for (int c = 0; c < 4; ++c) if (kb + kl + c < K) x[c] = bp[c];
        }
        v4h bh, bl;
        for (int c = 0; c < 4; ++c) {
          _Float16 hi = (_Float16)x[c];
          bh[c] = hi;
          bl[c] = (_Float16)((x[c] - (float)hi) * 1024.f);
        }
        *(v4h*)&Bh[row][kl] = bh;
        *(v4h*)&Bl[row][kl] = bl;
      }
    }
    __syncthreads();
    v8h af[4];
    for (int mt = 0; mt < 4; ++mt) {
      const int r = wm * 64 + mt * 16 + l15;
      af[mt] = *(const v8h*)&As[r][q * 8];
    }
    for (int nt = 0; nt < 4; ++nt) {
      const int r = wn * 64 + nt * 16 + l15;
      v8h bh = *(const v8h*)&Bh[r][q * 8];
      v8h bl = *(const v8h*)&Bl[r][q * 8];
      for (int mt = 0; mt < 4; ++mt) {
        accH[mt][nt] = __builtin_amdgcn_mfma_f32_16x16x32_f16(af[mt], bh, accH[mt][nt], 0, 0, 0);
        accL[mt][nt] = __builtin_amdgcn_mfma_f32_16x16x32_f16(af[mt], bl, accL[mt][nt], 0, 0, 0);
      }
    }
    __syncthreads();
  }
  for (int nt = 0; nt < 4; ++nt) {
    const int n = n0 + wn * 64 + nt * 16 + l15;
    const float bv = bias[n];
    for (int mt = 0; mt < 4; ++mt) {
      for (int r = 0; r < 4; ++r) {
        const int m = m0 + wm * 64 + mt * 16 + q * 4 + r;
        if (m < NM) {
          const float cv = accH[mt][nt][r] + accL[mt][nt][r] * (1.f / 1024.f) + bv;
          Cxg[(long)m * NG + n] = (_Float16)cv;
        }
      }
    }
  }
}

// ---------------- fused 2-layer persistent GRU scan (tagged + counter rendezvous) ----
// 32 blocks x 384 thr = 6 waves = (mt in 0..2) x (kh in 0..1 K-halves).
// Exchange = r8/r9 hybrid: NO per-thread vmcnt drain, NO flags, NO fence.
//  - writers: tagged 8B atoms (tag<<32)|packed2xf16, relaxed agent-scope,
//    fire-and-forget, contiguous per-block regions PAY[par][slot*200+gb*8+gj].
//  - rendezvous: after __syncthreads (all stores ISSUED block-wide), tid 0
//    bumps CNT[slot&3] (4 monotonic counters, separate 128B lines, 8 adds
//    each). The add travels CONCURRENTLY with the payload flight. Readers
//    poll all 4 counters >= 8*(t+1): observing the count (>=1 RT after
//    issue) implies earlier-issued payloads have ~landed.
//  - readers: ONE batched MALL-direct tagged sweep (global_load_dwordx4
//    sc0 sc1, single vmcnt), validate tags in-register, retry ONLY missing
//    chunks (tags catch rare channel-reorder tails; r9's storm is gone
//    because the throttle delays the first sweep until writers are done).
// Tags: layer0 step t -> t+1; layer1 step t -> t. PAY+CNT zeroed by k_gemm0
// each launch (monotonic within launch; zero never a valid tag/count).
// Parity-2 overwrite safety: lockstep argument unchanged (a parity-p
// overwrite at step t+2 requires all blocks' counters through t+1, which
// requires their step-t reads of parity p to have completed).
__global__ __launch_bounds__(384) void k_scan2(
    const _Float16* __restrict__ xg,    // [NM][NG] f16, includes b_ih0
    const float* __restrict__ whh0,     // [NG][NH]
    const float* __restrict__ wih1,     // [NG][NH]
    const float* __restrict__ whh1,     // [NG][NH]
    const float* __restrict__ bhh0,     // [NG]
    const float* __restrict__ bih1,     // [NG]
    const float* __restrict__ bhh1,     // [NG]
    const float* __restrict__ hinit,    // [2][NB][NH]
    ull* __restrict__ PAY0,             // [2][6400] tagged h0 slots
    ull* __restrict__ PAY1,             // [2][6400] tagged h1 slots
    unsigned* __restrict__ CNT,         // 4 monotonic counters, 128B stride
    float* __restrict__ hfin0,          // d_out h0 slice
    float* __restrict__ hfin1)          // d_out h1 slice
{
  __shared__ __align__(16) _Float16 hs0[NB][520];
  __shared__ __align__(16) _Float16 hs1[NB][520];
  __shared__ float g0[2][48][28];   // gh0 partials per K-half
  __shared__ float gx[2][48][28];   // xg1 partials
  __shared__ float g1[2][48][28];   // gh1 partials
  const int tid = threadIdx.x;
  const int slot = blockIdx.x;
  const int u0 = slot * 16;
  const int w = tid >> 6, l = tid & 63;
  const int mt = w % 3, kh = w / 3;
  const int l15 = l & 15, q = l >> 4;

  // ---- W fragments -> registers (single f16) ----
  v8h a0[8], ax[8], a1[8];
  {
    const long base = (long)(mt * 512 + u0 + l15) * 512 + kh * 256 + q * 8;
    for (int ks = 0; ks < 8; ++ks) {
      float4 v0, v1;
      v8h h;
      v0 = *(const float4*)(whh0 + base + ks * 32);
      v1 = *(const float4*)(whh0 + base + ks * 32 + 4);
      h[0]=(_Float16)v0.x; h[1]=(_Float16)v0.y; h[2]=(_Float16)v0.z; h[3]=(_Float16)v0.w;
      h[4]=(_Float16)v1.x; h[5]=(_Float16)v1.y; h[6]=(_Float16)v1.z; h[7]=(_Float16)v1.w;
      a0[ks] = h;
      v0 = *(const float4*)(wih1 + base + ks * 32);
      v1 = *(const float4*)(wih1 + base + ks * 32 + 4);
      h[0]=(_Float16)v0.x; h[1]=(_Float16)v0.y; h[2]=(_Float16)v0.z; h[3]=(_Float16)v0.w;
      h[4]=(_Float16)v1.x; h[5]=(_Float16)v1.y; h[6]=(_Float16)v1.z; h[7]=(_Float16)v1.w;
      ax[ks] = h;
      v0 = *(const float4*)(whh1 + base + ks * 32);
      v1 = *(const float4*)(whh1 + base + ks * 32 + 4);
      h[0]=(_Float16)v0.x; h[1]=(_Float16)v0.y; h[2]=(_Float16)v0.z; h[3]=(_Float16)v0.w;
      h[4]=(_Float16)v1.x; h[5]=(_Float16)v1.y; h[6]=(_Float16)v1.z; h[7]=(_Float16)v1.w;
      a1[ks] = h;
    }
  }
  // ---- initial h stage ----
  for (int idx = tid; idx < NB * NH; idx += 384) {
    hs0[idx >> 9][idx & 511] = (_Float16)hinit[idx];
    hs1[idx >> 9][idx & 511] = (_Float16)hinit[NB * NH + idx];
  }
  __syncthreads();

  const bool ga = (tid < 200);         // (batch gb 0..24) x (gj 0..7), 2 units each
  const int gb = tid >> 3, gj = tid & 7;
  const int i0 = 2 * gj, i1 = i0 + 1;

  // exact fp32 recurrent state (thread-private: the same thread updates it)
  float h0p0 = 0.f, h0p1 = 0.f, h1p0 = 0.f, h1p1 = 0.f;
  float b0r0=0,b0z0=0,b0n0=0,b0r1=0,b0z1=0,b0n1=0;
  float xi_r0=0,xi_z0=0,xi_n0=0,xi_r1=0,xi_z1=0,xi_n1=0;
  float b1r0=0,b1z0=0,b1n0=0,b1r1=0,b1z1=0,b1n1=0;
  const _Float16* xp = xg + (long)(ga ? gb * NT : 0) * NG + u0 + i0;
  v2h xr = {(_Float16)0, (_Float16)0}, xz = xr, xn2 = xr;
  if (ga) {
    const int ug = u0 + i0;
    h0p0 = hinit[gb * 512 + ug];              h0p1 = hinit[gb * 512 + ug + 1];
    h1p0 = hinit[NB * NH + gb * 512 + ug];    h1p1 = hinit[NB * NH + gb * 512 + ug + 1];
    b0r0 = bhh0[ug];        b0r1 = bhh0[ug + 1];
    b0z0 = bhh0[512 + ug];  b0z1 = bhh0[512 + ug + 1];
    b0n0 = bhh0[1024 + ug]; b0n1 = bhh0[1024 + ug + 1];
    xi_r0 = bih1[ug];        xi_r1 = bih1[ug + 1];
    xi_z0 = bih1[512 + ug];  xi_z1 = bih1[512 + ug + 1];
    xi_n0 = bih1[1024 + ug]; xi_n1 = bih1[1024 + ug + 1];
    b1r0 = bhh1[ug];        b1r1 = bhh1[ug + 1];
    b1z0 = bhh1[512 + ug];  b1z1 = bhh1[512 + ug + 1];
    b1n0 = bhh1[1024 + ug]; b1n1 = bhh1[1024 + ug + 1];
    xr  = *(const v2h*)xp;
    xz  = *(const v2h*)(xp + 512);
    xn2 = *(const v2h*)(xp + 1024);
  }
  const int du = slot * 200 + gb * 8 + gj;   // writer slot within parity plane

#pragma unroll 1
  for (int t = 0; t <= NT; ++t) {
    // prefetch xg0(t+1) behind the MFMA phase
    v2h pr = {(_Float16)0, (_Float16)0}, pz = pr, pn = pr;
    if (ga && t + 1 < NT) {
      const _Float16* q2 = xp + NG;
      pr = *(const v2h*)q2;
      pz = *(const v2h*)(q2 + 512);
      pn = *(const v2h*)(q2 + 1024);
    }
    // ---- MFMA phase: gh0, xg1 (share h0 B-frags), gh1 ----
    {
      v4f c00 = {0,0,0,0}, c01 = c00, cx0 = c00, cx1 = c00, c10 = c00, c11 = c00;
      const int kq = kh * 256 + q * 8;
      for (int ks = 0; ks < 8; ++ks) {
        const int k = kq + ks * 32;
        v8h b00 = *(const v8h*)&hs0[l15][k];
        v8h b01 = *(const v8h*)&hs0[9 + l15][k];
        v8h b10 = *(const v8h*)&hs1[l15][k];
        v8h b11 = *(const v8h*)&hs1[9 + l15][k];
        c00 = __builtin_amdgcn_mfma_f32_16x16x32_f16(a0[ks], b00, c00, 0, 0, 0);
        c01 = __builtin_amdgcn_mfma_f32_16x16x32_f16(a0[ks], b01, c01, 0, 0, 0);
        cx0 = __builtin_amdgcn_mfma_f32_16x16x32_f16(ax[ks], b00, cx0, 0, 0, 0);
        cx1 = __builtin_amdgcn_mfma_f32_16x16x32_f16(ax[ks], b01, cx1, 0, 0, 0);
        c10 = __builtin_amdgcn_mfma_f32_16x16x32_f16(a1[ks], b10, c10, 0, 0, 0);
        c11 = __builtin_amdgcn_mfma_f32_16x16x32_f16(a1[ks], b11, c11, 0, 0, 0);
      }
      const int row = mt * 16 + q * 4;
      for (int r = 0; r < 4; ++r) {
        g0[kh][row + r][l15]     = c00[r];
        g0[kh][row + r][9 + l15] = c01[r];
        gx[kh][row + r][l15]     = cx0[r];
        gx[kh][row + r][9 + l15] = cx1[r];
        g1[kh][row + r][l15]     = c10[r];
        g1[kh][row + r][9 + l15] = c11[r];
      }
    }
    __syncthreads();   // ghs+g ready; all hs reads done -> sweep may overwrite hs
    // ---- gate phase: compute + fire-and-forget tagged stores ----
    if (ga) {
      if (t < NT) {
        // layer 0 step t: h0(t+1)
        float hr0 = g0[0][i0][gb]      + g0[1][i0][gb]      + b0r0;
        float hz0 = g0[0][16+i0][gb]   + g0[1][16+i0][gb]   + b0z0;
        float hn0 = g0[0][32+i0][gb]   + g0[1][32+i0][gb]   + b0n0;
        float hr1 = g0[0][i1][gb]      + g0[1][i1][gb]      + b0r1;
        float hz1 = g0[0][16+i1][gb]   + g0[1][16+i1][gb]   + b0z1;
        float hn1 = g0[0][32+i1][gb]   + g0[1][32+i1][gb]   + b0n1;
        float r0 = fsigmoid((float)xr[0] + hr0);
        float z0 = fsigmoid((float)xz[0] + hz0);
        float n0 = ftanh((float)xn2[0] + r0 * hn0);
        float r1 = fsigmoid((float)xr[1] + hr1);
        float z1 = fsigmoid((float)xz[1] + hz1);
        float n1 = ftanh((float)xn2[1] + r1 * hn1);
        float h0n0 = (1.f - z0) * n0 + z0 * h0p0;
        float h0n1 = (1.f - z1) * n1 + z1 * h0p1;
        h0p0 = h0n0; h0p1 = h0n1;
        _Float16 f0 = (_Float16)h0n0, f1 = (_Float16)h0n1;
        unsigned pk = (unsigned)(*(unsigned short*)&f0) | ((unsigned)(*(unsigned short*)&f1) << 16);
        __hip_atomic_store(&PAY0[(size_t)((t + 1) & 1) * 6400 + du],
                           ((ull)(unsigned)(t + 1) << 32) | (ull)pk,
                           __ATOMIC_RELAXED, __HIP_MEMORY_SCOPE_AGENT);
        if (t == NT - 1) { hfin0[gb * 512 + u0 + i0] = h0n0; hfin0[gb * 512 + u0 + i1] = h0n1; }
      }
      if (t >= 1) {
        // layer 1 step t-1: h1(t) from h1(t-1) and out0(t-1)=h0(t)=hs0
        float xrr0 = gx[0][i0][gb]    + gx[1][i0][gb]    + xi_r0;
        float xzz0 = gx[0][16+i0][gb] + gx[1][16+i0][gb] + xi_z0;
        float xnn0 = gx[0][32+i0][gb] + gx[1][32+i0][gb] + xi_n0;
        float xrr1 = gx[0][i1][gb]    + gx[1][i1][gb]    + xi_r1;
        float xzz1 = gx[0][16+i1][gb] + gx[1][16+i1][gb] + xi_z1;
        float xnn1 = gx[0][32+i1][gb] + gx[1][32+i1][gb] + xi_n1;
        float hr0 = g1[0][i0][gb]     + g1[1][i0][gb]    + b1r0;
        float hz0 = g1[0][16+i0][gb]  + g1[1][16+i0][gb] + b1z0;
        float hn0 = g1[0][32+i0][gb]  + g1[1][32+i0][gb] + b1n0;
        float hr1 = g1[0][i1][gb]     + g1[1][i1][gb]    + b1r1;
        float hz1 = g1[0][16+i1][gb]  + g1[1][16+i1][gb] + b1z1;
        float hn1 = g1[0][32+i1][gb]  + g1[1][32+i1][gb] + b1n1;
        float r0 = fsigmoid(xrr0 + hr0);
        float z0 = fsigmoid(xzz0 + hz0);
        float n0 = ftanh(xnn0 + r0 * hn0);
        float r1 = fsigmoid(xrr1 + hr1);
        float z1 = fsigmoid(xzz1 + hz1);
        float n1 = ftanh(xnn1 + r1 * hn1);
        float h1n0 = (1.f - z0) * n0 + z0 * h1p0;
        float h1n1 = (1.f - z1) * n1 + z1 * h1p1;
        h1p0 = h1n0; h1p1 = h1n1;
        if (t < NT) {
          _Float16 f0 = (_Float16)h1n0, f1 = (_Float16)h1n1;
          unsigned pk = (unsigned)(*(unsigned short*)&f0) | ((unsigned)(*(unsigned short*)&f1) << 16);
          __hip_atomic_store(&PAY1[(size_t)(t & 1) * 6400 + du],
                             ((ull)(unsigned)t << 32) | (ull)pk,
                             __ATOMIC_RELAXED, __HIP_MEMORY_SCOPE_AGENT);
        }
        if (t == NT) { hfin1[gb * 512 + u0 + i0] = h1n0; hfin1[gb * 512 + u0 + i1] = h1n1; }
      }
    }
    // ---- rendezvous + throttled tagged sweep ----
    if (t < NT) {
      __syncthreads();               // all payload stores ISSUED block-wide
      if (tid == 0)
        __hip_atomic_fetch_add(&CNT[(slot & 3) * 32], 1u,
                               __ATOMIC_RELAXED, __HIP_MEMORY_SCOPE_AGENT);
      const unsigned tgt = 8u * (unsigned)(t + 1);
      for (;;) {
        unsigned c0 = __hip_atomic_load(&CNT[0],  __ATOMIC_RELAXED, __HIP_MEMORY_SCOPE_AGENT);
        unsigned c1 = __hip_atomic_load(&CNT[32], __ATOMIC_RELAXED, __HIP_MEMORY_SCOPE_AGENT);
        unsigned c2 = __hip_atomic_load(&CNT[64], __ATOMIC_RELAXED, __HIP_MEMORY_SCOPE_AGENT);
        unsigned c3 = __hip_atomic_load(&CNT[96], __ATOMIC_RELAXED, __HIP_MEMORY_SCOPE_AGENT);
        if (c0 >= tgt && c1 >= tgt && c2 >= tgt && c3 >= tgt) break;
        __builtin_amdgcn_s_sleep(1);
      }
      const char* P0 = (const char*)(PAY0 + (size_t)((t + 1) & 1) * 6400);
      const char* P1 = (const char*)(PAY1 + (size_t)(t & 1) * 6400);
      const unsigned w0 = (unsigned)(t + 1), w1 = (unsigned)t;
      const unsigned FULL = 0x3FFFFu;      // 9 chunks x 2 slots
      unsigned ok0 = 0, ok1 = (t == 0) ? FULL : 0u;
#pragma unroll
      for (int k = 0; k < 9; ++k)
        if (tid + 384 * k >= 3200) { ok0 |= 3u << (2 * k); ok1 |= 3u << (2 * k); }
      while (ok0 != FULL || ok1 != FULL) {
        v4i a[9], b[9];
#pragma unroll
        for (int k = 0; k < 9; ++k) {
          const int c = tid + 384 * k;     // 16B chunk = 2 tagged slots
          if (((ok0 >> (2 * k)) & 3u) != 3u)
            asm volatile("global_load_dwordx4 %0, %1, off sc0 sc1"
                         : "=v"(a[k]) : "v"(P0 + 16 * (size_t)c) : "memory");
          if (((ok1 >> (2 * k)) & 3u) != 3u)
            asm volatile("global_load_dwordx4 %0, %1, off sc0 sc1"
                         : "=v"(b[k]) : "v"(P1 + 16 * (size_t)c) : "memory");
        }
        asm volatile("s_waitcnt vmcnt(0)" ::: "memory");
        __builtin_amdgcn_sched_barrier(0);
#pragma unroll
        for (int k = 0; k < 9; ++k) {
          const int c = tid + 384 * k;
#pragma unroll
          for (int j = 0; j < 2; ++j) {
            const unsigned bit = 1u << (2 * k + j);
            const int sg = 2 * c + j;      // global slot id
            if (!(ok0 & bit) && (unsigned)a[k][2 * j + 1] == w0) {
              ok0 |= bit;
              const int bb = sg / 200, r = sg - bb * 200;
              *(unsigned*)&hs0[r >> 3][bb * 16 + 2 * (r & 7)] = (unsigned)a[k][2 * j];
            }
            if (!(ok1 & bit) && (unsigned)b[k][2 * j + 1] == w1) {
              ok1 |= bit;
              const int bb = sg / 200, r = sg - bb * 200;
              *(unsigned*)&hs1[r >> 3][bb * 16 + 2 * (r & 7)] = (unsigned)b[k][2 * j];
            }
          }
        }
      }
      __syncthreads();   // hs complete before next MFMA; g free for overwrite
    }
    xr = pr; xz = pz; xn2 = pn; xp += NG;
  }
}

// ---------------- final FC + sigmoid ----------------
__global__ __launch_bounds__(256) void k_final(
    const float* __restrict__ h1, const float* __restrict__ fcw,
    const float* __restrict__ fcb, float* __restrict__ sig)
{
  __shared__ float red[25][8];
  const int tid = threadIdx.x;
  const int b = tid >> 3, p = tid & 7;
  if (b < 25) {
    float s = 0.f;
    for (int k = p * 64; k < p * 64 + 64; ++k) s += h1[b * 512 + k] * fcw[k];
    red[b][p] = s;
  }
  __syncthreads();
  if (b < 25 && p == 0) {
    float d = red[b][0] + red[b][1] + red[b][2] + red[b][3]
            + red[b][4] + red[b][5] + red[b][6] + red[b][7];
    sig[b] = 1.f / (1.f + __expf(-(d + fcb[0])));
  }
}

extern "C" void kernel_launch(void* const* d_in, const int* in_sizes, int n_in,
                              void* d_out, int out_size, void* d_ws, size_t ws_size,
                              hipStream_t stream)
{
  (void)in_sizes; (void)n_in; (void)out_size;
  const int*   words  = (const int*)d_in[0];
  const float* hidden = (const float*)d_in[1];
  const float* emb    = (const float*)d_in[2];
  const float* w_ih0  = (const float*)d_in[3];
  const float* w_hh0  = (const float*)d_in[4];
  const float* b_ih0  = (const float*)d_in[5];
  const float* b_hh0  = (const float*)d_in[6];
  const float* w_ih1  = (const float*)d_in[7];
  const float* w_hh1  = (const float*)d_in[8];
  const float* b_ih1  = (const float*)d_in[9];
  const float* b_hh1  = (const float*)d_in[10];
  const float* fcw    = (const float*)d_in[11];
  const float* fcb    = (const float*)d_in[12];
  float* out = (float*)d_out;
  char* ws = (char*)d_ws;

  // ws: [0,256) pad | XG f16 46.08MB | PAY0 2x6400 ull | PAY1 2x6400 ull | CNT 2KB
  const size_t NEED = 256 + 46080000 + 2 * 51200 + 2 * 51200 + 2048;
  if (ws_size < NEED) return;

  _Float16* XG   = (_Float16*)(ws + 256);
  ull*      PAY0 = (ull*)(ws + 256 + 46080000);
  ull*      PAY1 = PAY0 + 2 * 6400;
  unsigned* CNT  = (unsigned*)(PAY1 + 2 * 6400);

  dim3 gg(118, 12);
  k_gemm0<<<gg, dim3(256), 0, stream>>>(words, emb, w_ih0, b_ih0, XG, PAY0);
  k_scan2<<<dim3(32), dim3(384), 0, stream>>>(XG, w_hh0, w_ih1, w_hh1,
                                              b_hh0, b_ih1, b_hh1, hidden,
                                              PAY0, PAY1, CNT,
                                              out + 25, out + 25 + NB * NH);
  k_final<<<dim3(1), dim3(256), 0, stream>>>(out + 25 + NB * NH, fcw, fcb, out);
}

// Round 11
// 2932.910 us; speedup vs baseline: 1.7286x; 1.7286x over previous
//
#include <hip/hip_runtime.h>

#define NV 100000
#define ND 300
#define NH 512
#define NB 25
#define NT 600
#define NM 15000   // NB*NT
#define NG 1536    // 3*NH

typedef _Float16 v8h __attribute__((ext_vector_type(8)));
typedef _Float16 v4h __attribute__((ext_vector_type(4)));
typedef _Float16 v2h __attribute__((ext_vector_type(2)));
typedef float    v4f __attribute__((ext_vector_type(4)));
typedef int      v4i __attribute__((ext_vector_type(4)));
typedef unsigned long long ull;

static __device__ __forceinline__ float fsigmoid(float x) {
  return __builtin_amdgcn_rcpf(1.f + __expf(-x));
}
static __device__ __forceinline__ float ftanh(float x) {
  return 1.f - 2.f * __builtin_amdgcn_rcpf(1.f + __expf(2.f * x));
}

// ---------------- GEMM: Cxg[m][n] = emb[words[m]]·w_ih0[n] + b_ih0[n], f16 out ----
__global__ __launch_bounds__(256) void k_gemm0(
    const int* __restrict__ words, const float* __restrict__ emb,
    const float* __restrict__ Bw, const float* __restrict__ bias,
    _Float16* __restrict__ Cxg, unsigned* __restrict__ EPOCH)
{
  // reset scan handshake flags (stream-ordered before k_scan2)
  if (blockIdx.x == 0 && blockIdx.y == 0 && threadIdx.x < 32)
    __hip_atomic_store(&EPOCH[threadIdx.x * 16], 0u,
                       __ATOMIC_RELAXED, __HIP_MEMORY_SCOPE_AGENT);

  constexpr int K = ND;
  constexpr int NKT = (K + 31) / 32;
  __shared__ _Float16 As[128][40];
  __shared__ _Float16 Bh[128][40];
  __shared__ _Float16 Bl[128][40];
  const int tid = threadIdx.x;
  const int m0 = blockIdx.x * 128, n0 = blockIdx.y * 128;
  const int w = tid >> 6, l = tid & 63;
  const int wm = w >> 1, wn = w & 1;
  const int l15 = l & 15, q = l >> 4;

  v4f accH[4][4], accL[4][4];
  for (int a = 0; a < 4; ++a)
    for (int b = 0; b < 4; ++b) {
      v4f z = {0.f, 0.f, 0.f, 0.f};
      accH[a][b] = z; accL[a][b] = z;
    }

#pragma unroll 1
  for (int kt = 0; kt < NKT; ++kt) {
    const int kb = kt * 32;
    for (int jj = 0; jj < 4; ++jj) {
      const int F = tid + 256 * jj;
      const int row = F >> 3;
      const int kl = (F & 7) * 4;
      {
        const int m = m0 + row;
        float x0 = 0.f, x1 = 0.f, x2 = 0.f, x3 = 0.f;
        if (m < NM) {
          const int word = words[m];
          const float* ap = emb + (long)word * ND + kb + kl;
          if (kb + kl + 3 < K) {
            float4 v = *(const float4*)ap;
            x0 = v.x; x1 = v.y; x2 = v.z; x3 = v.w;
          } else {
            if (kb + kl + 0 < K) x0 = ap[0];
            if (kb + kl + 1 < K) x1 = ap[1];
            if (kb + kl + 2 < K) x2 = ap[2];
            if (kb + kl + 3 < K) x3 = ap[3];
          }
        }
        v4h hv; hv[0]=(_Float16)x0; hv[1]=(_Float16)x1; hv[2]=(_Float16)x2; hv[3]=(_Float16)x3;
        *(v4h*)&As[row][kl] = hv;
      }
      {
        const int n = n0 + row;
        const float* bp = Bw + (long)n * K + kb + kl;
        float x[4] = {0.f, 0.f, 0.f, 0.f};
        if (kb + kl + 3 < K) {
          float4 v = *(const float4*)bp;
          x[0] = v.x; x[1] = v.y; x[2] = v.z; x[3] = v.w;
        } else {
          for (int c = 0; c < 4; ++c) if (kb + kl + c < K) x[c] = bp[c];
        }
        v4h bh, bl;
        for (int c = 0; c < 4; ++c) {
          _Float16 hi = (_Float16)x[c];
          bh[c] = hi;
          bl[c] = (_Float16)((x[c] - (float)hi) * 1024.f);
        }
        *(v4h*)&Bh[row][kl] = bh;
        *(v4h*)&Bl[row][kl] = bl;
      }
    }
    __syncthreads();
    v8h af[4];
    for (int mt = 0; mt < 4; ++mt) {
      const int r = wm * 64 + mt * 16 + l15;
      af[mt] = *(const v8h*)&As[r][q * 8];
    }
    for (int nt = 0; nt < 4; ++nt) {
      const int r = wn * 64 + nt * 16 + l15;
      v8h bh = *(const v8h*)&Bh[r][q * 8];
      v8h bl = *(const v8h*)&Bl[r][q * 8];
      for (int mt = 0; mt < 4; ++mt) {
        accH[mt][nt] = __builtin_amdgcn_mfma_f32_16x16x32_f16(af[mt], bh, accH[mt][nt], 0, 0, 0);
        accL[mt][nt] = __builtin_amdgcn_mfma_f32_16x16x32_f16(af[mt], bl, accL[mt][nt], 0, 0, 0);
      }
    }
    __syncthreads();
  }
  for (int nt = 0; nt < 4; ++nt) {
    const int n = n0 + wn * 64 + nt * 16 + l15;
    const float bv = bias[n];
    for (int mt = 0; mt < 4; ++mt) {
      for (int r = 0; r < 4; ++r) {
        const int m = m0 + wm * 64 + mt * 16 + q * 4 + r;
        if (m < NM) {
          const float cv = accH[mt][nt][r] + accL[mt][nt][r] * (1.f / 1024.f) + bv;
          Cxg[(long)m * NG + n] = (_Float16)cv;
        }
      }
    }
  }
}

// ---------------- fused 2-layer persistent GRU scan ----------------
// 32 blocks x 384 thr = 6 waves = (mt in 0..2) x (kh in 0..1 K-halves).
// Verified-best exchange (r8, 2506us scan / 4.18us per step):
//  - payload: untagged packed f16 pairs, parity-2 buffers, per-block
//    contiguous regions (PAY[parity][slot][200] u32), written as 8B
//    agent-scope atomic stores by even threads (odd value via __shfl_xor).
//  - readiness: per-block EPOCH flag (64B-padded), stored AFTER
//    s_waitcnt vmcnt(0) + barrier => flag implies payload at coherence point.
//    (The drain is load-bearing: r10's counter-rendezvous without it raced
//    the payload flight and retry-stormed, +86% scan time.)
//  - consumer: spin on the 32 flags (agent atomic loads, MALL-direct), then
//    ONE MALL-direct uncached sweep: global_load_dwordx4 sc0 sc1 (bypasses
//    L1+L2 -> reads drained data straight from MALL; NO acquire fence,
//    NO per-step buffer_inv, L2 stays warm for the xg stream).
//    vmcnt(0) + sched_barrier(0) before the dependent LDS writes.
// Plateau arithmetic (ledger r0-r10): drain ~1 RT + flag-flight/discovery
// ~1.3 RT + sweep ~1 RT + compute ~0.7us + barriers ~ 4.15us/step x 600.
// Closed branches: tags w/o rendezvous (r9), tags w/ counter (r10), stagger
// (r7), fence'd cached sweep (r2/r6), XCD-local (r4/r5 harness-fatal).
// Parity-2 safety (lockstep): block Y writes payload parity (t+3)&1 only
// after its iter t+1 spin saw all EPOCH >= t+2; block X sets EPOCH=t+2 only
// after its iter t payload reads (parity (t+1)&1) completed. So overwrites
// can't precede reads. Flags reset by k_gemm0 (stream-ordered); spin uses >=
// so stale values cannot deadlock.
__global__ __launch_bounds__(384) void k_scan2(
    const _Float16* __restrict__ xg,    // [NM][NG] f16, includes b_ih0
    const float* __restrict__ whh0,     // [NG][NH]
    const float* __restrict__ wih1,     // [NG][NH]
    const float* __restrict__ whh1,     // [NG][NH]
    const float* __restrict__ bhh0,     // [NG]
    const float* __restrict__ bih1,     // [NG]
    const float* __restrict__ bhh1,     // [NG]
    const float* __restrict__ hinit,    // [2][NB][NH]
    unsigned* __restrict__ PAY0,        // [2][32][200] packed h0 pairs
    unsigned* __restrict__ PAY1,        // [2][32][200] packed h1 pairs
    unsigned* __restrict__ EPOCH,       // [32*16] per-block epoch flags
    float* __restrict__ hfin0,          // d_out h0 slice
    float* __restrict__ hfin1)          // d_out h1 slice
{
  __shared__ __align__(16) _Float16 hs0[NB][520];
  __shared__ __align__(16) _Float16 hs1[NB][520];
  __shared__ float g0[2][48][28];   // gh0 partials per K-half
  __shared__ float gx[2][48][28];   // xg1 partials
  __shared__ float g1[2][48][28];   // gh1 partials
  const int tid = threadIdx.x;
  const int slot = blockIdx.x;
  const int u0 = slot * 16;
  const int w = tid >> 6, l = tid & 63;
  const int mt = w % 3, kh = w / 3;
  const int l15 = l & 15, q = l >> 4;

  // ---- W fragments -> registers (single f16) ----
  v8h a0[8], ax[8], a1[8];
  {
    const long base = (long)(mt * 512 + u0 + l15) * 512 + kh * 256 + q * 8;
    for (int ks = 0; ks < 8; ++ks) {
      float4 v0, v1;
      v8h h;
      v0 = *(const float4*)(whh0 + base + ks * 32);
      v1 = *(const float4*)(whh0 + base + ks * 32 + 4);
      h[0]=(_Float16)v0.x; h[1]=(_Float16)v0.y; h[2]=(_Float16)v0.z; h[3]=(_Float16)v0.w;
      h[4]=(_Float16)v1.x; h[5]=(_Float16)v1.y; h[6]=(_Float16)v1.z; h[7]=(_Float16)v1.w;
      a0[ks] = h;
      v0 = *(const float4*)(wih1 + base + ks * 32);
      v1 = *(const float4*)(wih1 + base + ks * 32 + 4);
      h[0]=(_Float16)v0.x; h[1]=(_Float16)v0.y; h[2]=(_Float16)v0.z; h[3]=(_Float16)v0.w;
      h[4]=(_Float16)v1.x; h[5]=(_Float16)v1.y; h[6]=(_Float16)v1.z; h[7]=(_Float16)v1.w;
      ax[ks] = h;
      v0 = *(const float4*)(whh1 + base + ks * 32);
      v1 = *(const float4*)(whh1 + base + ks * 32 + 4);
      h[0]=(_Float16)v0.x; h[1]=(_Float16)v0.y; h[2]=(_Float16)v0.z; h[3]=(_Float16)v0.w;
      h[4]=(_Float16)v1.x; h[5]=(_Float16)v1.y; h[6]=(_Float16)v1.z; h[7]=(_Float16)v1.w;
      a1[ks] = h;
    }
  }
  // ---- initial h stage ----
  for (int idx = tid; idx < NB * NH; idx += 384) {
    hs0[idx >> 9][idx & 511] = (_Float16)hinit[idx];
    hs1[idx >> 9][idx & 511] = (_Float16)hinit[NB * NH + idx];
  }
  __syncthreads();

  const bool ga = (tid < 200);         // (batch gb 0..24) x (gj 0..7), 2 units each
  const int gb = tid >> 3, gj = tid & 7;
  const int i0 = 2 * gj, i1 = i0 + 1;

  // exact fp32 recurrent state (thread-private: the same thread updates it)
  float h0p0 = 0.f, h0p1 = 0.f, h1p0 = 0.f, h1p1 = 0.f;
  float b0r0=0,b0z0=0,b0n0=0,b0r1=0,b0z1=0,b0n1=0;
  float xi_r0=0,xi_z0=0,xi_n0=0,xi_r1=0,xi_z1=0,xi_n1=0;
  float b1r0=0,b1z0=0,b1n0=0,b1r1=0,b1z1=0,b1n1=0;
  const _Float16* xp = xg + (long)(ga ? gb * NT : 0) * NG + u0 + i0;
  v2h xr = {(_Float16)0, (_Float16)0}, xz = xr, xn2 = xr;
  if (ga) {
    const int ug = u0 + i0;
    h0p0 = hinit[gb * 512 + ug];              h0p1 = hinit[gb * 512 + ug + 1];
    h1p0 = hinit[NB * NH + gb * 512 + ug];    h1p1 = hinit[NB * NH + gb * 512 + ug + 1];
    b0r0 = bhh0[ug];        b0r1 = bhh0[ug + 1];
    b0z0 = bhh0[512 + ug];  b0z1 = bhh0[512 + ug + 1];
    b0n0 = bhh0[1024 + ug]; b0n1 = bhh0[1024 + ug + 1];
    xi_r0 = bih1[ug];        xi_r1 = bih1[ug + 1];
    xi_z0 = bih1[512 + ug];  xi_z1 = bih1[512 + ug + 1];
    xi_n0 = bih1[1024 + ug]; xi_n1 = bih1[1024 + ug + 1];
    b1r0 = bhh1[ug];        b1r1 = bhh1[ug + 1];
    b1z0 = bhh1[512 + ug];  b1z1 = bhh1[512 + ug + 1];
    b1n0 = bhh1[1024 + ug]; b1n1 = bhh1[1024 + ug + 1];
    xr  = *(const v2h*)xp;
    xz  = *(const v2h*)(xp + 512);
    xn2 = *(const v2h*)(xp + 1024);
  }
  // per-block contiguous payload: ull index within region
  const int du = gb * 4 + (gj >> 1);   // 0..99

#pragma unroll 1
  for (int t = 0; t <= NT; ++t) {
    // prefetch xg0(t+1) behind the MFMA phase
    v2h pr = {(_Float16)0, (_Float16)0}, pz = pr, pn = pr;
    if (ga && t + 1 < NT) {
      const _Float16* q2 = xp + NG;
      pr = *(const v2h*)q2;
      pz = *(const v2h*)(q2 + 512);
      pn = *(const v2h*)(q2 + 1024);
    }
    // ---- MFMA phase: gh0, xg1 (share h0 B-frags), gh1 ----
    {
      v4f c00 = {0,0,0,0}, c01 = c00, cx0 = c00, cx1 = c00, c10 = c00, c11 = c00;
      const int kq = kh * 256 + q * 8;
      for (int ks = 0; ks < 8; ++ks) {
        const int k = kq + ks * 32;
        v8h b00 = *(const v8h*)&hs0[l15][k];
        v8h b01 = *(const v8h*)&hs0[9 + l15][k];
        v8h b10 = *(const v8h*)&hs1[l15][k];
        v8h b11 = *(const v8h*)&hs1[9 + l15][k];
        c00 = __builtin_amdgcn_mfma_f32_16x16x32_f16(a0[ks], b00, c00, 0, 0, 0);
        c01 = __builtin_amdgcn_mfma_f32_16x16x32_f16(a0[ks], b01, c01, 0, 0, 0);
        cx0 = __builtin_amdgcn_mfma_f32_16x16x32_f16(ax[ks], b00, cx0, 0, 0, 0);
        cx1 = __builtin_amdgcn_mfma_f32_16x16x32_f16(ax[ks], b01, cx1, 0, 0, 0);
        c10 = __builtin_amdgcn_mfma_f32_16x16x32_f16(a1[ks], b10, c10, 0, 0, 0);
        c11 = __builtin_amdgcn_mfma_f32_16x16x32_f16(a1[ks], b11, c11, 0, 0, 0);
      }
      const int row = mt * 16 + q * 4;
      for (int r = 0; r < 4; ++r) {
        g0[kh][row + r][l15]     = c00[r];
        g0[kh][row + r][9 + l15] = c01[r];
        gx[kh][row + r][l15]     = cx0[r];
        gx[kh][row + r][9 + l15] = cx1[r];
        g1[kh][row + r][l15]     = c10[r];
        g1[kh][row + r][9 + l15] = c11[r];
      }
    }
    __syncthreads();   // ghs ready; all hs reads done -> restage may overwrite hs
    // ---- gate phase ----
    if (ga) {
      if (t < NT) {
        // layer 0 step t: h0(t+1)
        float hr0 = g0[0][i0][gb]      + g0[1][i0][gb]      + b0r0;
        float hz0 = g0[0][16+i0][gb]   + g0[1][16+i0][gb]   + b0z0;
        float hn0 = g0[0][32+i0][gb]   + g0[1][32+i0][gb]   + b0n0;
        float hr1 = g0[0][i1][gb]      + g0[1][i1][gb]      + b0r1;
        float hz1 = g0[0][16+i1][gb]   + g0[1][16+i1][gb]   + b0z1;
        float hn1 = g0[0][32+i1][gb]   + g0[1][32+i1][gb]   + b0n1;
        float r0 = fsigmoid((float)xr[0] + hr0);
        float z0 = fsigmoid((float)xz[0] + hz0);
        float n0 = ftanh((float)xn2[0] + r0 * hn0);
        float r1 = fsigmoid((float)xr[1] + hr1);
        float z1 = fsigmoid((float)xz[1] + hz1);
        float n1 = ftanh((float)xn2[1] + r1 * hn1);
        float h0n0 = (1.f - z0) * n0 + z0 * h0p0;
        float h0n1 = (1.f - z1) * n1 + z1 * h0p1;
        h0p0 = h0n0; h0p1 = h0n1;
        _Float16 f0 = (_Float16)h0n0, f1 = (_Float16)h0n1;
        unsigned pk = (unsigned)(*(unsigned short*)&f0) | ((unsigned)(*(unsigned short*)&f1) << 16);
        const unsigned pko = (unsigned)__shfl_xor((int)pk, 1);
        if (!(tid & 1)) {
          ull* H0 = (ull*)PAY0 + (size_t)((t + 1) & 1) * 3200 + slot * 100 + du;
          __hip_atomic_store(H0, (ull)pk | ((ull)pko << 32),
                             __ATOMIC_RELAXED, __HIP_MEMORY_SCOPE_AGENT);
        }
        if (t == NT - 1) { hfin0[gb * 512 + u0 + i0] = h0n0; hfin0[gb * 512 + u0 + i1] = h0n1; }
      }
      if (t >= 1) {
        // layer 1 step t-1: h1(t) from h1(t-1) and out0(t-1)=h0(t)=hs0
        float xrr0 = gx[0][i0][gb]    + gx[1][i0][gb]    + xi_r0;
        float xzz0 = gx[0][16+i0][gb] + gx[1][16+i0][gb] + xi_z0;
        float xnn0 = gx[0][32+i0][gb] + gx[1][32+i0][gb] + xi_n0;
        float xrr1 = gx[0][i1][gb]    + gx[1][i1][gb]    + xi_r1;
        float xzz1 = gx[0][16+i1][gb] + gx[1][16+i1][gb] + xi_z1;
        float xnn1 = gx[0][32+i1][gb] + gx[1][32+i1][gb] + xi_n1;
        float hr0 = g1[0][i0][gb]     + g1[1][i0][gb]    + b1r0;
        float hz0 = g1[0][16+i0][gb]  + g1[1][16+i0][gb] + b1z0;
        float hn0 = g1[0][32+i0][gb]  + g1[1][32+i0][gb] + b1n0;
        float hr1 = g1[0][i1][gb]     + g1[1][i1][gb]    + b1r1;
        float hz1 = g1[0][16+i1][gb]  + g1[1][16+i1][gb] + b1z1;
        float hn1 = g1[0][32+i1][gb]  + g1[1][32+i1][gb] + b1n1;
        float r0 = fsigmoid(xrr0 + hr0);
        float z0 = fsigmoid(xzz0 + hz0);
        float n0 = ftanh(xnn0 + r0 * hn0);
        float r1 = fsigmoid(xrr1 + hr1);
        float z1 = fsigmoid(xzz1 + hz1);
        float n1 = ftanh(xnn1 + r1 * hn1);
        float h1n0 = (1.f - z0) * n0 + z0 * h1p0;
        float h1n1 = (1.f - z1) * n1 + z1 * h1p1;
        h1p0 = h1n0; h1p1 = h1n1;
        _Float16 f0 = (_Float16)h1n0, f1 = (_Float16)h1n1;
        unsigned pk = (unsigned)(*(unsigned short*)&f0) | ((unsigned)(*(unsigned short*)&f1) << 16);
        const unsigned pko = (unsigned)__shfl_xor((int)pk, 1);
        if (t < NT && !(tid & 1)) {
          ull* H1 = (ull*)PAY1 + (size_t)(t & 1) * 3200 + slot * 100 + du;
          __hip_atomic_store(H1, (ull)pk | ((ull)pko << 32),
                             __ATOMIC_RELAXED, __HIP_MEMORY_SCOPE_AGENT);
        }
        if (t == NT) { hfin1[gb * 512 + u0 + i0] = h1n0; hfin1[gb * 512 + u0 + i1] = h1n1; }
      }
    }
    if (t < NT) {
      // ---- publish: flag implies all this block's payload stores completed ----
      asm volatile("s_waitcnt vmcnt(0)" ::: "memory");
      __syncthreads();
      if (tid == 0)
        __hip_atomic_store(&EPOCH[slot * 16], (unsigned)(t + 1),
                           __ATOMIC_RELAXED, __HIP_MEMORY_SCOPE_AGENT);
      // ---- wait: all 32 blocks reached epoch t+1 ----
      const unsigned tgt = (unsigned)(t + 1);
      while (__hip_atomic_load(&EPOCH[(tid & 31) * 16],
                               __ATOMIC_RELAXED, __HIP_MEMORY_SCOPE_AGENT) < tgt)
        __builtin_amdgcn_s_sleep(1);
      __syncthreads();
      // ---- single MALL-direct payload sweep: sc0 sc1 16B/lane, NO fence ----
      // chunk g = s*50 + r2 : 8 consecutive h-units of batch (r2>>1) from
      // block s -> one contiguous 16B LDS write at hs[r2>>1][s*16 + 8*(r2&1)].
      const char* P0 = (const char*)(PAY0 + (size_t)((t + 1) & 1) * 6400);
      const char* P1 = (const char*)(PAY1 + (size_t)(t & 1) * 6400);
      v4i av[5], bv[5];
#pragma unroll
      for (int kk = 0; kk < 5; ++kk) {
        const int g = tid + 384 * kk;
        if (g < 1600) {
          asm volatile("global_load_dwordx4 %0, %1, off sc0 sc1"
                       : "=v"(av[kk]) : "v"(P0 + 16 * (size_t)g) : "memory");
          if (t > 0)
            asm volatile("global_load_dwordx4 %0, %1, off sc0 sc1"
                         : "=v"(bv[kk]) : "v"(P1 + 16 * (size_t)g) : "memory");
        }
      }
      asm volatile("s_waitcnt vmcnt(0)" ::: "memory");
      __builtin_amdgcn_sched_barrier(0);
#pragma unroll
      for (int kk = 0; kk < 5; ++kk) {
        const int g = tid + 384 * kk;
        if (g < 1600) {
          const int s  = g / 50;
          const int r2 = g - s * 50;
          const int b2 = r2 >> 1;
          const int uo = s * 16 + 8 * (r2 & 1);
          *(v4i*)&hs0[b2][uo] = av[kk];
          if (t > 0) *(v4i*)&hs1[b2][uo] = bv[kk];
        }
      }
      __syncthreads();
    }
    xr = pr; xz = pz; xn2 = pn; xp += NG;
  }
}

// ---------------- final FC + sigmoid ----------------
__global__ __launch_bounds__(256) void k_final(
    const float* __restrict__ h1, const float* __restrict__ fcw,
    const float* __restrict__ fcb, float* __restrict__ sig)
{
  __shared__ float red[25][8];
  const int tid = threadIdx.x;
  const int b = tid >> 3, p = tid & 7;
  if (b < 25) {
    float s = 0.f;
    for (int k = p * 64; k < p * 64 + 64; ++k) s += h1[b * 512 + k] * fcw[k];
    red[b][p] = s;
  }
  __syncthreads();
  if (b < 25 && p == 0) {
    float d = red[b][0] + red[b][1] + red[b][2] + red[b][3]
            + red[b][4] + red[b][5] + red[b][6] + red[b][7];
    sig[b] = 1.f / (1.f + __expf(-(d + fcb[0])));
  }
}

extern "C" void kernel_launch(void* const* d_in, const int* in_sizes, int n_in,
                              void* d_out, int out_size, void* d_ws, size_t ws_size,
                              hipStream_t stream)
{
  (void)in_sizes; (void)n_in; (void)out_size;
  const int*   words  = (const int*)d_in[0];
  const float* hidden = (const float*)d_in[1];
  const float* emb    = (const float*)d_in[2];
  const float* w_ih0  = (const float*)d_in[3];
  const float* w_hh0  = (const float*)d_in[4];
  const float* b_ih0  = (const float*)d_in[5];
  const float* b_hh0  = (const float*)d_in[6];
  const float* w_ih1  = (const float*)d_in[7];
  const float* w_hh1  = (const float*)d_in[8];
  const float* b_ih1  = (const float*)d_in[9];
  const float* b_hh1  = (const float*)d_in[10];
  const float* fcw    = (const float*)d_in[11];
  const float* fcb    = (const float*)d_in[12];
  float* out = (float*)d_out;
  char* ws = (char*)d_ws;

  // ws: [0,256) pad | XG f16 46.08MB | PAY0 2x6400 u32 | PAY1 2x6400 u32 | EPOCH 32x16 u32
  const size_t NEED = 256 + 46080000 + 2 * 25600 + 2 * 25600 + 2048;
  if (ws_size < NEED) return;

  _Float16* XG    = (_Float16*)(ws + 256);
  unsigned* PAY0  = (unsigned*)(ws + 256 + 46080000);
  unsigned* PAY1  = PAY0 + 2 * 6400;
  unsigned* EPOCH = PAY1 + 2 * 6400;

  dim3 gg(118, 12);
  k_gemm0<<<gg, dim3(256), 0, stream>>>(words, emb, w_ih0, b_ih0, XG, EPOCH);
  k_scan2<<<dim3(32), dim3(384), 0, stream>>>(XG, w_hh0, w_ih1, w_hh1,
                                              b_hh0, b_ih1, b_hh1, hidden,
                                              PAY0, PAY1, EPOCH,
                                              out + 25, out + 25 + NB * NH);
  k_final<<<dim3(1), dim3(256), 0, stream>>>(out + 25 + NB * NH, fcw, fcb, out);
}

// Round 12
// 2807.777 us; speedup vs baseline: 1.8056x; 1.0446x over previous
//
#include <hip/hip_runtime.h>

#define NV 100000
#define ND 300
#define NH 512
#define NB 25
#define NT 600
#define NM 15000   // NB*NT
#define NG 1536    // 3*NH

typedef _Float16 v8h __attribute__((ext_vector_type(8)));
typedef _Float16 v4h __attribute__((ext_vector_type(4)));
typedef _Float16 v2h __attribute__((ext_vector_type(2)));
typedef float    v4f __attribute__((ext_vector_type(4)));
typedef int      v4i __attribute__((ext_vector_type(4)));
typedef unsigned long long ull;

static __device__ __forceinline__ float fsigmoid(float x) {
  return __builtin_amdgcn_rcpf(1.f + __expf(-x));
}
static __device__ __forceinline__ float ftanh(float x) {
  return 1.f - 2.f * __builtin_amdgcn_rcpf(1.f + __expf(2.f * x));
}

// ---------------- GEMM: Cxg[m][n] = emb[words[m]]·w_ih0[n] + b_ih0[n], f16 out ----
// v2: hoisted gather addresses (words[m]/row pointers loaded ONCE, not per kt)
// + register double-buffered staging: kt+1's global loads issue right after
// the staging barrier of kt, so the MFMA phase hides the emb-gather latency.
// Conversion math / LDS layout / MFMA / epilogue unchanged => bit-identical.
__global__ __launch_bounds__(256) void k_gemm0(
    const int* __restrict__ words, const float* __restrict__ emb,
    const float* __restrict__ Bw, const float* __restrict__ bias,
    _Float16* __restrict__ Cxg, unsigned* __restrict__ EPOCH)
{
  // reset scan handshake flags (stream-ordered before k_scan2)
  if (blockIdx.x == 0 && blockIdx.y == 0 && threadIdx.x < 32)
    __hip_atomic_store(&EPOCH[threadIdx.x * 16], 0u,
                       __ATOMIC_RELAXED, __HIP_MEMORY_SCOPE_AGENT);

  constexpr int K = ND;
  constexpr int NKT = (K + 31) / 32;
  __shared__ _Float16 As[128][40];
  __shared__ _Float16 Bh[128][40];
  __shared__ _Float16 Bl[128][40];
  const int tid = threadIdx.x;
  const int m0 = blockIdx.x * 128, n0 = blockIdx.y * 128;
  const int w = tid >> 6, l = tid & 63;
  const int wm = w >> 1, wn = w & 1;
  const int l15 = l & 15, q = l >> 4;

  // ---- hoisted per-thread staging state (rows fixed across kt) ----
  const float* aptr[4];
  const float* bptr[4];
  int rowv[4], klv[4];
  bool mval[4];
  for (int jj = 0; jj < 4; ++jj) {
    const int F = tid + 256 * jj;
    const int row = F >> 3;
    const int kl = (F & 7) * 4;
    rowv[jj] = row; klv[jj] = kl;
    const int m = m0 + row;
    mval[jj] = (m < NM);
    const int word = mval[jj] ? words[m] : 0;
    aptr[jj] = emb + (long)word * ND + kl;
    bptr[jj] = Bw + (long)(n0 + row) * K + kl;
  }

  v4f accH[4][4], accL[4][4];
  for (int a = 0; a < 4; ++a)
    for (int b = 0; b < 4; ++b) {
      v4f z = {0.f, 0.f, 0.f, 0.f};
      accH[a][b] = z; accL[a][b] = z;
    }

  float4 ra[4], rb[4];
  // guarded register load of K-chunk kb into ra/rb
  auto LOADK = [&](int kb) {
    for (int jj = 0; jj < 4; ++jj) {
      const int kk = kb + klv[jj];
      float4 va = {0.f, 0.f, 0.f, 0.f}, vb = {0.f, 0.f, 0.f, 0.f};
      if (kk + 3 < K) {
        if (mval[jj]) va = *(const float4*)(aptr[jj] + kb);
        vb = *(const float4*)(bptr[jj] + kb);
      } else {
        float t[4] = {0.f, 0.f, 0.f, 0.f}, u[4] = {0.f, 0.f, 0.f, 0.f};
        for (int c = 0; c < 4; ++c)
          if (kk + c < K) {
            if (mval[jj]) t[c] = aptr[jj][kb + c];
            u[c] = bptr[jj][kb + c];
          }
        va.x = t[0]; va.y = t[1]; va.z = t[2]; va.w = t[3];
        vb.x = u[0]; vb.y = u[1]; vb.z = u[2]; vb.w = u[3];
      }
      ra[jj] = va; rb[jj] = vb;
    }
  };

  LOADK(0);
#pragma unroll 1
  for (int kt = 0; kt < NKT; ++kt) {
    // ---- stage phase: convert preloaded regs -> LDS (math identical to v1) ----
    for (int jj = 0; jj < 4; ++jj) {
      v4h hv;
      hv[0] = (_Float16)ra[jj].x; hv[1] = (_Float16)ra[jj].y;
      hv[2] = (_Float16)ra[jj].z; hv[3] = (_Float16)ra[jj].w;
      *(v4h*)&As[rowv[jj]][klv[jj]] = hv;
      float xx[4] = {rb[jj].x, rb[jj].y, rb[jj].z, rb[jj].w};
      v4h bh, bl;
      for (int c = 0; c < 4; ++c) {
        _Float16 hi = (_Float16)xx[c];
        bh[c] = hi;
        bl[c] = (_Float16)((xx[c] - (float)hi) * 1024.f);
      }
      *(v4h*)&Bh[rowv[jj]][klv[jj]] = bh;
      *(v4h*)&Bl[rowv[jj]][klv[jj]] = bl;
    }
    __syncthreads();
    // ---- issue next chunk's loads; latency hides under the MFMA phase ----
    if (kt + 1 < NKT) LOADK((kt + 1) * 32);
    // ---- MFMA phase (unchanged) ----
    v8h af[4];
    for (int mt = 0; mt < 4; ++mt) {
      const int r = wm * 64 + mt * 16 + l15;
      af[mt] = *(const v8h*)&As[r][q * 8];
    }
    for (int nt = 0; nt < 4; ++nt) {
      const int r = wn * 64 + nt * 16 + l15;
      v8h bh = *(const v8h*)&Bh[r][q * 8];
      v8h bl = *(const v8h*)&Bl[r][q * 8];
      for (int mt = 0; mt < 4; ++mt) {
        accH[mt][nt] = __builtin_amdgcn_mfma_f32_16x16x32_f16(af[mt], bh, accH[mt][nt], 0, 0, 0);
        accL[mt][nt] = __builtin_amdgcn_mfma_f32_16x16x32_f16(af[mt], bl, accL[mt][nt], 0, 0, 0);
      }
    }
    __syncthreads();
  }
  for (int nt = 0; nt < 4; ++nt) {
    const int n = n0 + wn * 64 + nt * 16 + l15;
    const float bv = bias[n];
    for (int mt = 0; mt < 4; ++mt) {
      for (int r = 0; r < 4; ++r) {
        const int m = m0 + wm * 64 + mt * 16 + q * 4 + r;
        if (m < NM) {
          const float cv = accH[mt][nt][r] + accL[mt][nt][r] * (1.f / 1024.f) + bv;
          Cxg[(long)m * NG + n] = (_Float16)cv;
        }
      }
    }
  }
}

// ---------------- fused 2-layer persistent GRU scan ----------------
// 32 blocks x 384 thr = 6 waves = (mt in 0..2) x (kh in 0..1 K-halves).
// Verified-best exchange (r8/r11, 2490us scan / 4.15us per step):
//  - payload: untagged packed f16 pairs, parity-2 buffers, per-block
//    contiguous regions (PAY[parity][slot][200] u32), written as 8B
//    agent-scope atomic stores by even threads (odd value via __shfl_xor).
//  - readiness: per-block EPOCH flag (64B-padded), stored AFTER
//    s_waitcnt vmcnt(0) + barrier => flag implies payload at coherence point.
//    (The drain is load-bearing: r10's counter-rendezvous without it raced
//    the payload flight and retry-stormed, +86% scan time.)
//  - consumer: spin on the 32 flags (agent atomic loads, MALL-direct), then
//    ONE MALL-direct uncached sweep: global_load_dwordx4 sc0 sc1 (bypasses
//    L1+L2 -> reads drained data straight from MALL; NO acquire fence,
//    NO per-step buffer_inv, L2 stays warm for the xg stream).
//    vmcnt(0) + sched_barrier(0) before the dependent LDS writes.
// Plateau arithmetic (ledger r0-r11): drain ~1 RT + flag-flight/discovery
// ~1.3 RT + sweep ~1 RT + compute ~0.7us + barriers ~ 4.15us/step x 600.
// Closed branches: tags w/o rendezvous (r9), tags w/ counter (r10), stagger
// (r7), fence'd cached sweep (r2/r6), XCD-local (r4/r5 harness-fatal).
// Parity-2 safety (lockstep): block Y writes payload parity (t+3)&1 only
// after its iter t+1 spin saw all EPOCH >= t+2; block X sets EPOCH=t+2 only
// after its iter t payload reads (parity (t+1)&1) completed. So overwrites
// can't precede reads. Flags reset by k_gemm0 (stream-ordered); spin uses >=
// so stale values cannot deadlock.
__global__ __launch_bounds__(384) void k_scan2(
    const _Float16* __restrict__ xg,    // [NM][NG] f16, includes b_ih0
    const float* __restrict__ whh0,     // [NG][NH]
    const float* __restrict__ wih1,     // [NG][NH]
    const float* __restrict__ whh1,     // [NG][NH]
    const float* __restrict__ bhh0,     // [NG]
    const float* __restrict__ bih1,     // [NG]
    const float* __restrict__ bhh1,     // [NG]
    const float* __restrict__ hinit,    // [2][NB][NH]
    unsigned* __restrict__ PAY0,        // [2][32][200] packed h0 pairs
    unsigned* __restrict__ PAY1,        // [2][32][200] packed h1 pairs
    unsigned* __restrict__ EPOCH,       // [32*16] per-block epoch flags
    float* __restrict__ hfin0,          // d_out h0 slice
    float* __restrict__ hfin1)          // d_out h1 slice
{
  __shared__ __align__(16) _Float16 hs0[NB][520];
  __shared__ __align__(16) _Float16 hs1[NB][520];
  __shared__ float g0[2][48][28];   // gh0 partials per K-half
  __shared__ float gx[2][48][28];   // xg1 partials
  __shared__ float g1[2][48][28];   // gh1 partials
  const int tid = threadIdx.x;
  const int slot = blockIdx.x;
  const int u0 = slot * 16;
  const int w = tid >> 6, l = tid & 63;
  const int mt = w % 3, kh = w / 3;
  const int l15 = l & 15, q = l >> 4;

  // ---- W fragments -> registers (single f16) ----
  v8h a0[8], ax[8], a1[8];
  {
    const long base = (long)(mt * 512 + u0 + l15) * 512 + kh * 256 + q * 8;
    for (int ks = 0; ks < 8; ++ks) {
      float4 v0, v1;
      v8h h;
      v0 = *(const float4*)(whh0 + base + ks * 32);
      v1 = *(const float4*)(whh0 + base + ks * 32 + 4);
      h[0]=(_Float16)v0.x; h[1]=(_Float16)v0.y; h[2]=(_Float16)v0.z; h[3]=(_Float16)v0.w;
      h[4]=(_Float16)v1.x; h[5]=(_Float16)v1.y; h[6]=(_Float16)v1.z; h[7]=(_Float16)v1.w;
      a0[ks] = h;
      v0 = *(const float4*)(wih1 + base + ks * 32);
      v1 = *(const float4*)(wih1 + base + ks * 32 + 4);
      h[0]=(_Float16)v0.x; h[1]=(_Float16)v0.y; h[2]=(_Float16)v0.z; h[3]=(_Float16)v0.w;
      h[4]=(_Float16)v1.x; h[5]=(_Float16)v1.y; h[6]=(_Float16)v1.z; h[7]=(_Float16)v1.w;
      ax[ks] = h;
      v0 = *(const float4*)(whh1 + base + ks * 32);
      v1 = *(const float4*)(whh1 + base + ks * 32 + 4);
      h[0]=(_Float16)v0.x; h[1]=(_Float16)v0.y; h[2]=(_Float16)v0.z; h[3]=(_Float16)v0.w;
      h[4]=(_Float16)v1.x; h[5]=(_Float16)v1.y; h[6]=(_Float16)v1.z; h[7]=(_Float16)v1.w;
      a1[ks] = h;
    }
  }
  // ---- initial h stage ----
  for (int idx = tid; idx < NB * NH; idx += 384) {
    hs0[idx >> 9][idx & 511] = (_Float16)hinit[idx];
    hs1[idx >> 9][idx & 511] = (_Float16)hinit[NB * NH + idx];
  }
  __syncthreads();

  const bool ga = (tid < 200);         // (batch gb 0..24) x (gj 0..7), 2 units each
  const int gb = tid >> 3, gj = tid & 7;
  const int i0 = 2 * gj, i1 = i0 + 1;

  // exact fp32 recurrent state (thread-private: the same thread updates it)
  float h0p0 = 0.f, h0p1 = 0.f, h1p0 = 0.f, h1p1 = 0.f;
  float b0r0=0,b0z0=0,b0n0=0,b0r1=0,b0z1=0,b0n1=0;
  float xi_r0=0,xi_z0=0,xi_n0=0,xi_r1=0,xi_z1=0,xi_n1=0;
  float b1r0=0,b1z0=0,b1n0=0,b1r1=0,b1z1=0,b1n1=0;
  const _Float16* xp = xg + (long)(ga ? gb * NT : 0) * NG + u0 + i0;
  v2h xr = {(_Float16)0, (_Float16)0}, xz = xr, xn2 = xr;
  if (ga) {
    const int ug = u0 + i0;
    h0p0 = hinit[gb * 512 + ug];              h0p1 = hinit[gb * 512 + ug + 1];
    h1p0 = hinit[NB * NH + gb * 512 + ug];    h1p1 = hinit[NB * NH + gb * 512 + ug + 1];
    b0r0 = bhh0[ug];        b0r1 = bhh0[ug + 1];
    b0z0 = bhh0[512 + ug];  b0z1 = bhh0[512 + ug + 1];
    b0n0 = bhh0[1024 + ug]; b0n1 = bhh0[1024 + ug + 1];
    xi_r0 = bih1[ug];        xi_r1 = bih1[ug + 1];
    xi_z0 = bih1[512 + ug];  xi_z1 = bih1[512 + ug + 1];
    xi_n0 = bih1[1024 + ug]; xi_n1 = bih1[1024 + ug + 1];
    b1r0 = bhh1[ug];        b1r1 = bhh1[ug + 1];
    b1z0 = bhh1[512 + ug];  b1z1 = bhh1[512 + ug + 1];
    b1n0 = bhh1[1024 + ug]; b1n1 = bhh1[1024 + ug + 1];
    xr  = *(const v2h*)xp;
    xz  = *(const v2h*)(xp + 512);
    xn2 = *(const v2h*)(xp + 1024);
  }
  // per-block contiguous payload: ull index within region
  const int du = gb * 4 + (gj >> 1);   // 0..99

#pragma unroll 1
  for (int t = 0; t <= NT; ++t) {
    // prefetch xg0(t+1) behind the MFMA phase
    v2h pr = {(_Float16)0, (_Float16)0}, pz = pr, pn = pr;
    if (ga && t + 1 < NT) {
      const _Float16* q2 = xp + NG;
      pr = *(const v2h*)q2;
      pz = *(const v2h*)(q2 + 512);
      pn = *(const v2h*)(q2 + 1024);
    }
    // ---- MFMA phase: gh0, xg1 (share h0 B-frags), gh1 ----
    {
      v4f c00 = {0,0,0,0}, c01 = c00, cx0 = c00, cx1 = c00, c10 = c00, c11 = c00;
      const int kq = kh * 256 + q * 8;
      for (int ks = 0; ks < 8; ++ks) {
        const int k = kq + ks * 32;
        v8h b00 = *(const v8h*)&hs0[l15][k];
        v8h b01 = *(const v8h*)&hs0[9 + l15][k];
        v8h b10 = *(const v8h*)&hs1[l15][k];
        v8h b11 = *(const v8h*)&hs1[9 + l15][k];
        c00 = __builtin_amdgcn_mfma_f32_16x16x32_f16(a0[ks], b00, c00, 0, 0, 0);
        c01 = __builtin_amdgcn_mfma_f32_16x16x32_f16(a0[ks], b01, c01, 0, 0, 0);
        cx0 = __builtin_amdgcn_mfma_f32_16x16x32_f16(ax[ks], b00, cx0, 0, 0, 0);
        cx1 = __builtin_amdgcn_mfma_f32_16x16x32_f16(ax[ks], b01, cx1, 0, 0, 0);
        c10 = __builtin_amdgcn_mfma_f32_16x16x32_f16(a1[ks], b10, c10, 0, 0, 0);
        c11 = __builtin_amdgcn_mfma_f32_16x16x32_f16(a1[ks], b11, c11, 0, 0, 0);
      }
      const int row = mt * 16 + q * 4;
      for (int r = 0; r < 4; ++r) {
        g0[kh][row + r][l15]     = c00[r];
        g0[kh][row + r][9 + l15] = c01[r];
        gx[kh][row + r][l15]     = cx0[r];
        gx[kh][row + r][9 + l15] = cx1[r];
        g1[kh][row + r][l15]     = c10[r];
        g1[kh][row + r][9 + l15] = c11[r];
      }
    }
    __syncthreads();   // ghs ready; all hs reads done -> restage may overwrite hs
    // ---- gate phase ----
    if (ga) {
      if (t < NT) {
        // layer 0 step t: h0(t+1)
        float hr0 = g0[0][i0][gb]      + g0[1][i0][gb]      + b0r0;
        float hz0 = g0[0][16+i0][gb]   + g0[1][16+i0][gb]   + b0z0;
        float hn0 = g0[0][32+i0][gb]   + g0[1][32+i0][gb]   + b0n0;
        float hr1 = g0[0][i1][gb]      + g0[1][i1][gb]      + b0r1;
        float hz1 = g0[0][16+i1][gb]   + g0[1][16+i1][gb]   + b0z1;
        float hn1 = g0[0][32+i1][gb]   + g0[1][32+i1][gb]   + b0n1;
        float r0 = fsigmoid((float)xr[0] + hr0);
        float z0 = fsigmoid((float)xz[0] + hz0);
        float n0 = ftanh((float)xn2[0] + r0 * hn0);
        float r1 = fsigmoid((float)xr[1] + hr1);
        float z1 = fsigmoid((float)xz[1] + hz1);
        float n1 = ftanh((float)xn2[1] + r1 * hn1);
        float h0n0 = (1.f - z0) * n0 + z0 * h0p0;
        float h0n1 = (1.f - z1) * n1 + z1 * h0p1;
        h0p0 = h0n0; h0p1 = h0n1;
        _Float16 f0 = (_Float16)h0n0, f1 = (_Float16)h0n1;
        unsigned pk = (unsigned)(*(unsigned short*)&f0) | ((unsigned)(*(unsigned short*)&f1) << 16);
        const unsigned pko = (unsigned)__shfl_xor((int)pk, 1);
        if (!(tid & 1)) {
          ull* H0 = (ull*)PAY0 + (size_t)((t + 1) & 1) * 3200 + slot * 100 + du;
          __hip_atomic_store(H0, (ull)pk | ((ull)pko << 32),
                             __ATOMIC_RELAXED, __HIP_MEMORY_SCOPE_AGENT);
        }
        if (t == NT - 1) { hfin0[gb * 512 + u0 + i0] = h0n0; hfin0[gb * 512 + u0 + i1] = h0n1; }
      }
      if (t >= 1) {
        // layer 1 step t-1: h1(t) from h1(t-1) and out0(t-1)=h0(t)=hs0
        float xrr0 = gx[0][i0][gb]    + gx[1][i0][gb]    + xi_r0;
        float xzz0 = gx[0][16+i0][gb] + gx[1][16+i0][gb] + xi_z0;
        float xnn0 = gx[0][32+i0][gb] + gx[1][32+i0][gb] + xi_n0;
        float xrr1 = gx[0][i1][gb]    + gx[1][i1][gb]    + xi_r1;
        float xzz1 = gx[0][16+i1][gb] + gx[1][16+i1][gb] + xi_z1;
        float xnn1 = gx[0][32+i1][gb] + gx[1][32+i1][gb] + xi_n1;
        float hr0 = g1[0][i0][gb]     + g1[1][i0][gb]    + b1r0;
        float hz0 = g1[0][16+i0][gb]  + g1[1][16+i0][gb] + b1z0;
        float hn0 = g1[0][32+i0][gb]  + g1[1][32+i0][gb] + b1n0;
        float hr1 = g1[0][i1][gb]     + g1[1][i1][gb]    + b1r1;
        float hz1 = g1[0][16+i1][gb]  + g1[1][16+i1][gb] + b1z1;
        float hn1 = g1[0][32+i1][gb]  + g1[1][32+i1][gb] + b1n1;
        float r0 = fsigmoid(xrr0 + hr0);
        float z0 = fsigmoid(xzz0 + hz0);
        float n0 = ftanh(xnn0 + r0 * hn0);
        float r1 = fsigmoid(xrr1 + hr1);
        float z1 = fsigmoid(xzz1 + hz1);
        float n1 = ftanh(xnn1 + r1 * hn1);
        float h1n0 = (1.f - z0) * n0 + z0 * h1p0;
        float h1n1 = (1.f - z1) * n1 + z1 * h1p1;
        h1p0 = h1n0; h1p1 = h1n1;
        _Float16 f0 = (_Float16)h1n0, f1 = (_Float16)h1n1;
        unsigned pk = (unsigned)(*(unsigned short*)&f0) | ((unsigned)(*(unsigned short*)&f1) << 16);
        const unsigned pko = (unsigned)__shfl_xor((int)pk, 1);
        if (t < NT && !(tid & 1)) {
          ull* H1 = (ull*)PAY1 + (size_t)(t & 1) * 3200 + slot * 100 + du;
          __hip_atomic_store(H1, (ull)pk | ((ull)pko << 32),
                             __ATOMIC_RELAXED, __HIP_MEMORY_SCOPE_AGENT);
        }
        if (t == NT) { hfin1[gb * 512 + u0 + i0] = h1n0; hfin1[gb * 512 + u0 + i1] = h1n1; }
      }
    }
    if (t < NT) {
      // ---- publish: flag implies all this block's payload stores completed ----
      asm volatile("s_waitcnt vmcnt(0)" ::: "memory");
      __syncthreads();
      if (tid == 0)
        __hip_atomic_store(&EPOCH[slot * 16], (unsigned)(t + 1),
                           __ATOMIC_RELAXED, __HIP_MEMORY_SCOPE_AGENT);
      // ---- wait: all 32 blocks reached epoch t+1 ----
      const unsigned tgt = (unsigned)(t + 1);
      while (__hip_atomic_load(&EPOCH[(tid & 31) * 16],
                               __ATOMIC_RELAXED, __HIP_MEMORY_SCOPE_AGENT) < tgt)
        __builtin_amdgcn_s_sleep(1);
      __syncthreads();
      // ---- single MALL-direct payload sweep: sc0 sc1 16B/lane, NO fence ----
      // chunk g = s*50 + r2 : 8 consecutive h-units of batch (r2>>1) from
      // block s -> one contiguous 16B LDS write at hs[r2>>1][s*16 + 8*(r2&1)].
      const char* P0 = (const char*)(PAY0 + (size_t)((t + 1) & 1) * 6400);
      const char* P1 = (const char*)(PAY1 + (size_t)(t & 1) * 6400);
      v4i av[5], bv[5];
#pragma unroll
      for (int kk = 0; kk < 5; ++kk) {
        const int g = tid + 384 * kk;
        if (g < 1600) {
          asm volatile("global_load_dwordx4 %0, %1, off sc0 sc1"
                       : "=v"(av[kk]) : "v"(P0 + 16 * (size_t)g) : "memory");
          if (t > 0)
            asm volatile("global_load_dwordx4 %0, %1, off sc0 sc1"
                         : "=v"(bv[kk]) : "v"(P1 + 16 * (size_t)g) : "memory");
        }
      }
      asm volatile("s_waitcnt vmcnt(0)" ::: "memory");
      __builtin_amdgcn_sched_barrier(0);
#pragma unroll
      for (int kk = 0; kk < 5; ++kk) {
        const int g = tid + 384 * kk;
        if (g < 1600) {
          const int s  = g / 50;
          const int r2 = g - s * 50;
          const int b2 = r2 >> 1;
          const int uo = s * 16 + 8 * (r2 & 1);
          *(v4i*)&hs0[b2][uo] = av[kk];
          if (t > 0) *(v4i*)&hs1[b2][uo] = bv[kk];
        }
      }
      __syncthreads();
    }
    xr = pr; xz = pz; xn2 = pn; xp += NG;
  }
}

// ---------------- final FC + sigmoid ----------------
__global__ __launch_bounds__(256) void k_final(
    const float* __restrict__ h1, const float* __restrict__ fcw,
    const float* __restrict__ fcb, float* __restrict__ sig)
{
  __shared__ float red[25][8];
  const int tid = threadIdx.x;
  const int b = tid >> 3, p = tid & 7;
  if (b < 25) {
    float s = 0.f;
    for (int k = p * 64; k < p * 64 + 64; ++k) s += h1[b * 512 + k] * fcw[k];
    red[b][p] = s;
  }
  __syncthreads();
  if (b < 25 && p == 0) {
    float d = red[b][0] + red[b][1] + red[b][2] + red[b][3]
            + red[b][4] + red[b][5] + red[b][6] + red[b][7];
    sig[b] = 1.f / (1.f + __expf(-(d + fcb[0])));
  }
}

extern "C" void kernel_launch(void* const* d_in, const int* in_sizes, int n_in,
                              void* d_out, int out_size, void* d_ws, size_t ws_size,
                              hipStream_t stream)
{
  (void)in_sizes; (void)n_in; (void)out_size;
  const int*   words  = (const int*)d_in[0];
  const float* hidden = (const float*)d_in[1];
  const float* emb    = (const float*)d_in[2];
  const float* w_ih0  = (const float*)d_in[3];
  const float* w_hh0  = (const float*)d_in[4];
  const float* b_ih0  = (const float*)d_in[5];
  const float* b_hh0  = (const float*)d_in[6];
  const float* w_ih1  = (const float*)d_in[7];
  const float* w_hh1  = (const float*)d_in[8];
  const float* b_ih1  = (const float*)d_in[9];
  const float* b_hh1  = (const float*)d_in[10];
  const float* fcw    = (const float*)d_in[11];
  const float* fcb    = (const float*)d_in[12];
  float* out = (float*)d_out;
  char* ws = (char*)d_ws;

  // ws: [0,256) pad | XG f16 46.08MB | PAY0 2x6400 u32 | PAY1 2x6400 u32 | EPOCH 32x16 u32
  const size_t NEED = 256 + 46080000 + 2 * 25600 + 2 * 25600 + 2048;
  if (ws_size < NEED) return;

  _Float16* XG    = (_Float16*)(ws + 256);
  unsigned* PAY0  = (unsigned*)(ws + 256 + 46080000);
  unsigned* PAY1  = PAY0 + 2 * 6400;
  unsigned* EPOCH = PAY1 + 2 * 6400;

  dim3 gg(118, 12);
  k_gemm0<<<gg, dim3(256), 0, stream>>>(words, emb, w_ih0, b_ih0, XG, EPOCH);
  k_scan2<<<dim3(32), dim3(384), 0, stream>>>(XG, w_hh0, w_ih1, w_hh1,
                                              b_hh0, b_ih1, b_hh1, hidden,
                                              PAY0, PAY1, EPOCH,
                                              out + 25, out + 25 + NB * NH);
  k_final<<<dim3(1), dim3(256), 0, stream>>>(out + 25 + NB * NH, fcw, fcb, out);
}